// Round 9
// baseline (147.931 us; speedup 1.0000x reference)
//
#include <hip/hip_runtime.h>
#include <hip/hip_bf16.h>

constexpr int BATCH = 256;
constexpr int VOCAB = 128000;
constexpr int K = 256;
constexpr float IGNORED_C = -3000.0f;

// fast path params
constexpr int NCHUNK = 4;
constexpr int CHUNK = VOCAB / NCHUNK;   // 32000
constexpr int N4 = CHUNK / 4;           // 8000 float4 per chunk
constexpr int NSAMP = 1024;             // samples per chunk
constexpr int CAP = 1024;               // candidate cap per chunk
constexpr int R0 = 20;                  // initial sample rank: E[count]~655
constexpr int N2 = NCHUNK * CAP;        // 4096 candidates per row into k2

// fallback path params
constexpr int FB_BINS = 8192;
constexpr int FB_SHIFT = 19;
constexpr int FB_CAND = 2048;

// order-preserving f32 -> u32 map (larger float => larger key)
__device__ __forceinline__ unsigned mono(unsigned u) {
    return (u & 0x80000000u) ? ~u : (u | 0x80000000u);
}
__device__ __forceinline__ float inv_mono(unsigned k) {
    unsigned u = (k & 0x80000000u) ? (k ^ 0x80000000u) : ~k;
    return __uint_as_float(u);
}

// block-wide exact count over the streamed chunk:
// ngt = #(key > T), neq = #(key == T && local_idx <= X). No retained arrays.
__device__ __forceinline__ void count_pass(const float4* __restrict__ rp4,
                                           int tid, int wave, int lane,
                                           unsigned* wred, unsigned T, unsigned X,
                                           unsigned& ngt, unsigned& neq)
{
    unsigned cgt = 0u, ceq = 0u;
    for (int i = tid; i < N4; i += 512) {
        const float4 v = rp4[i];
        const unsigned base = 4u * (unsigned)i;
        unsigned kk;
        kk = mono(__float_as_uint(v.x)); cgt += (kk > T); ceq += ((kk == T) && (base + 0u <= X));
        kk = mono(__float_as_uint(v.y)); cgt += (kk > T); ceq += ((kk == T) && (base + 1u <= X));
        kk = mono(__float_as_uint(v.z)); cgt += (kk > T); ceq += ((kk == T) && (base + 2u <= X));
        kk = mono(__float_as_uint(v.w)); cgt += (kk > T); ceq += ((kk == T) && (base + 3u <= X));
    }
    #pragma unroll
    for (int off = 32; off >= 1; off >>= 1) {
        cgt += __shfl_xor(cgt, off);
        ceq += __shfl_xor(ceq, off);
    }
    __syncthreads();                    // protect wred reuse across passes
    if (lane == 0) { wred[wave] = cgt; wred[8 + wave] = ceq; }
    __syncthreads();
    unsigned g = 0u, e = 0u;
    #pragma unroll
    for (int w = 0; w < 8; ++w) { g += wred[w]; e += wred[8 + w]; }
    ngt = g; neq = e;
}

// ============================================================================
// K1: per (row, chunk): sampled threshold + single streaming collect pass.
// No LDS histogram (R2/R3/R8: 1 LDS atomic per element ~= the 50+ us floor),
// no register-resident data (R4-7: spill / occupancy death). Exact via
// count verification + rank/key/index binary-search retries (stream from L3).
// ============================================================================
__global__ __launch_bounds__(512)
void k1_select(const float* __restrict__ logits,
               unsigned long long* __restrict__ ws_cand)
{
    __shared__ unsigned samp[NSAMP];
    __shared__ unsigned long long cand[CAP];
    __shared__ unsigned wred[16];
    __shared__ unsigned ccount;

    const int tid = threadIdx.x;
    const int wave = tid >> 6, lane = tid & 63;
    const int row = blockIdx.x >> 2;            // NCHUNK == 4
    const int chunk = blockIdx.x & 3;
    const int gbase = chunk * CHUNK;
    const float* rowp = logits + (size_t)row * VOCAB + gbase;
    const float4* rp4 = reinterpret_cast<const float4*>(rowp);

    // ---- 1024 strided samples (stride 31: max pos 31713 < 32000) ----
    samp[tid]       = mono(__float_as_uint(rowp[tid * 31]));
    samp[tid + 512] = mono(__float_as_uint(rowp[(tid + 512) * 31]));
    __syncthreads();

    // ---- bitonic sort samples descending (u32, LDS) ----
    for (int k = 2; k <= NSAMP; k <<= 1) {
        for (int j = k >> 1; j > 0; j >>= 1) {
            for (int i = tid; i < NSAMP; i += 512) {
                const int ixj = i ^ j;
                if (ixj > i) {
                    const unsigned a = samp[i], b = samp[ixj];
                    const bool sw = ((i & k) == 0) ? (a < b) : (a > b);
                    if (sw) { samp[i] = b; samp[ixj] = a; }
                }
            }
            __syncthreads();
        }
    }

    // ---- threshold retry loop (common path: exactly one collect pass) ----
    int rlo = -1, rhi = NSAMP, r = R0;
    unsigned T = samp[R0];
    unsigned X = 0xFFFFFFFFu;
    bool tie = false;
    unsigned cc = 0u;

    for (int guard = 0; guard < 64; ++guard) {
        if (tid == 0) ccount = 0u;
        __syncthreads();
        for (int i = tid; i < N4; i += 512) {
            const float4 v = rp4[i];
            const unsigned base = 4u * (unsigned)i;
#define TRYC(kx, off) { \
        const unsigned kk_ = (kx); \
        const bool sel_ = tie ? ((kk_ > T) || ((kk_ == T) && ((base + (off)) <= X))) \
                              : (kk_ >= T); \
        if (sel_) { \
            const unsigned p_ = atomicAdd(&ccount, 1u); \
            if (p_ < (unsigned)CAP) \
                cand[p_] = ((unsigned long long)kk_ << 32) \
                         | (unsigned)(~(unsigned)(gbase + (int)(base + (off)))); \
        } }
            TRYC(mono(__float_as_uint(v.x)), 0u)
            TRYC(mono(__float_as_uint(v.y)), 1u)
            TRYC(mono(__float_as_uint(v.z)), 2u)
            TRYC(mono(__float_as_uint(v.w)), 3u)
#undef TRYC
        }
        __syncthreads();
        cc = ccount;
        __syncthreads();
        if (cc >= (unsigned)K && cc <= (unsigned)CAP) break;   // success
        if (tie) break;                                        // tie collect is exact-K (safety)

        // rank-space adjustment with proportional first guess
        if (cc < (unsigned)K) rlo = r; else rhi = r;
        if (rhi - rlo > 1) {
            const unsigned denom = (cc == 0u) ? 1u : cc;
            long long rn = ((long long)(r + 1) * 512ll) / (long long)denom - 1ll;
            int rni = (int)rn;
            if (rni <= rlo) rni = rlo + 1;
            if (rni >= rhi) rni = rhi - 1;
            r = rni; T = samp[r];
            continue;
        }
        // no sample rank works: key-space binary search for
        // T* = max key with n_ge(T*) >= K  (invariants: n_ge(klo)>=K, n_ge(khi)<K)
        unsigned klo = (rhi < NSAMP) ? samp[rhi] : 0u;
        unsigned khi = (rlo >= 0) ? samp[rlo] : 0xFFFFFFFFu;
        while (khi - klo > 1u) {
            const unsigned mid = klo + ((khi - klo) >> 1);
            unsigned g, e;
            count_pass(rp4, tid, wave, lane, wred, mid, 0xFFFFFFFFu, g, e);
            if (g + e >= (unsigned)K) klo = mid; else khi = mid;
        }
        T = klo;
        unsigned g, e;
        count_pass(rp4, tid, wave, lane, wred, T, 0xFFFFFFFFu, g, e);
        if (g + e <= (unsigned)CAP) { tie = false; continue; } // plain collect will succeed
        // heavy ties at T: ngt = g < K (since n_ge(T+1) < K); pick K-g smallest indices
        const unsigned target = (unsigned)K - g;
        int xlo = -1, xhi = CHUNK - 1;
        while (xhi - xlo > 1) {
            const int xm = (xlo + xhi) >> 1;
            unsigned g2, e2;
            count_pass(rp4, tid, wave, lane, wred, T, (unsigned)xm, g2, e2);
            if (e2 >= target) xhi = xm; else xlo = xm;
        }
        X = (unsigned)xhi;
        tie = true;                                            // next collect = exactly K
    }

    // ---- write unsorted candidates, zero-padded to CAP ----
    for (int i = tid; i < CAP; i += 512)
        ws_cand[(size_t)blockIdx.x * CAP + i] = ((unsigned)i < cc) ? cand[i] : 0ull;
}

// ============================================================================
// K2: per row: load 4x1024 candidates -> bitonic sort 4096 desc (exact order:
// value desc, idx asc via u64 key) -> top-256 pipeline -> ws.
// ============================================================================
__global__ __launch_bounds__(1024)
void k2_sortsel(const float* __restrict__ params,
                const unsigned long long* __restrict__ ws_cand,
                float* __restrict__ ws_v, float* __restrict__ ws_csum,
                int* __restrict__ ws_idx, float* __restrict__ ws_p0)
{
    __shared__ unsigned long long buf[N2];
    __shared__ float red[K];
    __shared__ float sc[K];

    const int row = blockIdx.x;
    const int tid = threadIdx.x;

    for (int i = tid; i < N2; i += 1024)
        buf[i] = ws_cand[(size_t)row * N2 + i];
    __syncthreads();

    // full bitonic sort, descending
    for (int k = 2; k <= N2; k <<= 1) {
        for (int j = k >> 1; j > 0; j >>= 1) {
            for (int i = tid; i < N2; i += 1024) {
                const int ixj = i ^ j;
                if (ixj > i) {
                    const unsigned long long a = buf[i], b = buf[ixj];
                    const bool sw = ((i & k) == 0) ? (a < b) : (a > b);
                    if (sw) { buf[i] = b; buf[ixj] = a; }
                }
            }
            __syncthreads();
        }
    }

    // pipeline on top-256: topk-mask -> /temp -> softmax -> cumsum
    const bool act = tid < K;
    const float topk_f = params[row * 3 + 0];
    const float temp   = params[row * 3 + 2];
    float v = 0.f;
    int myidx = 0;
    if (act) {
        const unsigned long long c = buf[tid];
        const float val = inv_mono((unsigned)(c >> 32));
        myidx = (int)(~(unsigned)c);
        const float x = (((float)tid) >= topk_f) ? IGNORED_C : val;
        v = x / temp;
        red[tid] = v;
    }
    __syncthreads();
    for (int s = K / 2; s > 0; s >>= 1) {
        if (tid < s) red[tid] = fmaxf(red[tid], red[tid + s]);
        __syncthreads();
    }
    const float m = red[0];
    __syncthreads();
    const float e = act ? expf(v - m) : 0.f;
    if (act) red[tid] = e;
    __syncthreads();
    for (int s = K / 2; s > 0; s >>= 1) {
        if (tid < s) red[tid] += red[tid + s];
        __syncthreads();
    }
    const float ssum = red[0];
    __syncthreads();
    const float p = e / ssum;
    if (act) sc[tid] = p;
    __syncthreads();
    for (int off = 1; off < K; off <<= 1) {
        float t = 0.f;
        if (act && tid >= off) t = sc[tid - off];
        __syncthreads();
        if (act) sc[tid] += t;
        __syncthreads();
    }
    if (act) {
        ws_v[row * K + tid]    = v;
        ws_csum[row * K + tid] = sc[tid];
        ws_idx[row * K + tid]  = myidx;
    }
    if (tid == 0) ws_p0[row] = p;   // probs[0] == csum[0]
}

// ============================================================================
// K3: global-min(p0) -> top-p mask -> softmax -> cumsum -> sample
// ============================================================================
__global__ __launch_bounds__(K)
void k3_sample(const float* __restrict__ params,
               const float* __restrict__ rand_u,
               const float* __restrict__ ws_v,
               const float* __restrict__ ws_csum,
               const int* __restrict__ ws_idx,
               const float* __restrict__ ws_p0,
               int* __restrict__ out)
{
    __shared__ float red[K];
    __shared__ float sc[K];
    const int row = blockIdx.x;
    const int tid = threadIdx.x;

    red[tid] = ws_p0[tid];          // BATCH == 256 == blockDim
    __syncthreads();
    for (int s = K / 2; s > 0; s >>= 1) {
        if (tid < s) red[tid] = fminf(red[tid], red[tid + s]);
        __syncthreads();
    }
    const float tpe = fmaxf(red[0], params[row * 3 + 1]);
    __syncthreads();

    const float csum = ws_csum[row * K + tid];
    const float v0   = ws_v[row * K + tid];
    const float v2 = ((csum > tpe) && (tid != 0)) ? IGNORED_C : v0;
    red[tid] = v2;
    __syncthreads();
    for (int s = K / 2; s > 0; s >>= 1) {
        if (tid < s) red[tid] = fmaxf(red[tid], red[tid + s]);
        __syncthreads();
    }
    const float m = red[0];
    __syncthreads();
    const float e = expf(v2 - m);
    red[tid] = e;
    __syncthreads();
    for (int s = K / 2; s > 0; s >>= 1) {
        if (tid < s) red[tid] += red[tid + s];
        __syncthreads();
    }
    const float ssum = red[0];
    __syncthreads();
    const float p = e / ssum;
    sc[tid] = p;
    __syncthreads();
    for (int off = 1; off < K; off <<= 1) {
        float t = (tid >= off) ? sc[tid - off] : 0.f;
        __syncthreads();
        sc[tid] += t;
        __syncthreads();
    }
    const float ru = rand_u[row];
    red[tid] = (ru > sc[tid]) ? 1.f : 0.f;
    __syncthreads();
    for (int s = K / 2; s > 0; s >>= 1) {
        if (tid < s) red[tid] += red[tid + s];
        __syncthreads();
    }
    if (tid == 0) {
        int sel = (int)red[0];
        if (sel > K - 1) sel = K - 1;
        out[row] = ws_idx[row * K + sel];
    }
}

// ============================================================================
// Fallback (round-1 proven): single block per row, used only if ws too small
// ============================================================================
__global__ __launch_bounds__(1024)
void fb_stage1(const float* __restrict__ logits,
               const float* __restrict__ params,
               float* __restrict__ ws_v,
               float* __restrict__ ws_csum,
               int* __restrict__ ws_idx,
               float* __restrict__ ws_p0)
{
    __shared__ unsigned hist[FB_BINS];
    __shared__ unsigned gsum[128];
    __shared__ unsigned long long cand[FB_CAND];
    __shared__ unsigned ccount;
    __shared__ int tbin;
    __shared__ float sv[K];
    __shared__ float se[K];
    __shared__ int   sidx[K];
    __shared__ float sred;

    const int row = blockIdx.x;
    const int tid = threadIdx.x;
    const float4* rp4 = reinterpret_cast<const float4*>(logits + (size_t)row * VOCAB);

    for (int i = tid; i < FB_BINS; i += 1024) hist[i] = 0u;
    __syncthreads();
    for (int i = tid; i < VOCAB / 4; i += 1024) {
        float4 v = rp4[i];
        atomicAdd(&hist[mono(__float_as_uint(v.x)) >> FB_SHIFT], 1u);
        atomicAdd(&hist[mono(__float_as_uint(v.y)) >> FB_SHIFT], 1u);
        atomicAdd(&hist[mono(__float_as_uint(v.z)) >> FB_SHIFT], 1u);
        atomicAdd(&hist[mono(__float_as_uint(v.w)) >> FB_SHIFT], 1u);
    }
    __syncthreads();
    if (tid < 128) {
        unsigned s = 0;
        for (int i = 0; i < 64; ++i) s += hist[tid * 64 + i];
        gsum[tid] = s;
    }
    __syncthreads();
    if (tid == 0) {
        unsigned acc = 0;
        int g = 127;
        for (; g > 0; --g) {
            if (acc + gsum[g] >= (unsigned)K) break;
            acc += gsum[g];
        }
        int t = g * 64;
        for (int bin = g * 64 + 63; bin >= g * 64; --bin) {
            acc += hist[bin];
            if (acc >= (unsigned)K) { t = bin; break; }
        }
        tbin = t;
        ccount = 0u;
    }
    __syncthreads();
    const unsigned tb = (unsigned)tbin;
    for (int i = tid; i < VOCAB / 4; i += 1024) {
        float4 v = rp4[i];
        const int base = i * 4;
        unsigned kk[4] = { mono(__float_as_uint(v.x)), mono(__float_as_uint(v.y)),
                           mono(__float_as_uint(v.z)), mono(__float_as_uint(v.w)) };
        #pragma unroll
        for (int c = 0; c < 4; ++c) {
            if ((kk[c] >> FB_SHIFT) >= tb) {
                unsigned p = atomicAdd(&ccount, 1u);
                if (p < FB_CAND)
                    cand[p] = ((unsigned long long)kk[c] << 32) | (unsigned)(~(base + c));
            }
        }
    }
    __syncthreads();
    for (int i = tid; i < FB_CAND; i += 1024)
        if ((unsigned)i >= ccount) cand[i] = 0ull;
    __syncthreads();
    for (int k = 2; k <= FB_CAND; k <<= 1) {
        for (int j = k >> 1; j > 0; j >>= 1) {
            for (int i = tid; i < FB_CAND; i += 1024) {
                int ixj = i ^ j;
                if (ixj > i) {
                    unsigned long long a = cand[i], b = cand[ixj];
                    bool sw = ((i & k) == 0) ? (a < b) : (a > b);
                    if (sw) { cand[i] = b; cand[ixj] = a; }
                }
            }
            __syncthreads();
        }
    }
    const float topk_f = params[row * 3 + 0];
    const float temp   = params[row * 3 + 2];
    if (tid < K) {
        unsigned long long c = cand[tid];
        float val = inv_mono((unsigned)(c >> 32));
        sidx[tid] = (int)(~(unsigned)c);
        float v = (((float)tid) >= topk_f) ? IGNORED_C : val;
        sv[tid] = v / temp;
    }
    __syncthreads();
    if (tid == 0) {
        float mm = sv[0];
        for (int i = 1; i < K; ++i) mm = fmaxf(mm, sv[i]);
        sred = mm;
    }
    __syncthreads();
    if (tid < K) se[tid] = expf(sv[tid] - sred);
    __syncthreads();
    if (tid == 0) {
        float s = 0.f;
        for (int i = 0; i < K; ++i) s += se[i];
        sred = s;
    }
    __syncthreads();
    if (tid < K) se[tid] = se[tid] / sred;
    __syncthreads();
    if (tid == 0) {
        float c = 0.f;
        for (int i = 0; i < K; ++i) { c += se[i]; se[i] = c; }
    }
    __syncthreads();
    if (tid < K) {
        ws_v[row * K + tid]    = sv[tid];
        ws_csum[row * K + tid] = se[tid];
        ws_idx[row * K + tid]  = sidx[tid];
    }
    if (tid == 0) ws_p0[row] = se[0];
}

extern "C" void kernel_launch(void* const* d_in, const int* in_sizes, int n_in,
                              void* d_out, int out_size, void* d_ws, size_t ws_size,
                              hipStream_t stream) {
    const float* logits = (const float*)d_in[0];
    const float* params = (const float*)d_in[1];
    const float* randu  = (const float*)d_in[2];
    int* out = (int*)d_out;
    char* ws = (char*)d_ws;

    const size_t cand_bytes = (size_t)BATCH * NCHUNK * CAP * 8;        // 8 MB
    const size_t tail_bytes = (size_t)3 * BATCH * K * 4 + BATCH * 4;   // 769 KB
    if (ws_size >= cand_bytes + tail_bytes) {
        unsigned long long* ws_cand = (unsigned long long*)ws;
        char* p = ws + cand_bytes;
        float* ws_v    = (float*)(p);
        float* ws_csum = (float*)(p + (size_t)BATCH * K * 4);
        int*   ws_idx  = (int*)  (p + (size_t)2 * BATCH * K * 4);
        float* ws_p0   = (float*)(p + (size_t)3 * BATCH * K * 4);
        hipLaunchKernelGGL(k1_select, dim3(BATCH * NCHUNK), dim3(512), 0, stream,
                           logits, ws_cand);
        hipLaunchKernelGGL(k2_sortsel, dim3(BATCH), dim3(1024), 0, stream,
                           params, ws_cand, ws_v, ws_csum, ws_idx, ws_p0);
        hipLaunchKernelGGL(k3_sample, dim3(BATCH), dim3(K), 0, stream,
                           params, randu, ws_v, ws_csum, ws_idx, ws_p0, out);
    } else {
        float* ws_v    = (float*)(ws);
        float* ws_csum = (float*)(ws + (size_t)BATCH * K * 4);
        int*   ws_idx  = (int*)  (ws + (size_t)2 * BATCH * K * 4);
        float* ws_p0   = (float*)(ws + (size_t)3 * BATCH * K * 4);
        hipLaunchKernelGGL(fb_stage1, dim3(BATCH), dim3(1024), 0, stream,
                           logits, params, ws_v, ws_csum, ws_idx, ws_p0);
        hipLaunchKernelGGL(k3_sample, dim3(BATCH), dim3(K), 0, stream,
                           params, randu, ws_v, ws_csum, ws_idx, ws_p0, out);
    }
}

// Round 10
// 78.971 us; speedup vs baseline: 1.8732x; 1.8732x over previous
//
#include <hip/hip_runtime.h>
#include <hip/hip_bf16.h>

constexpr int BATCH = 256;
constexpr int VOCAB = 128000;
constexpr int K = 256;
constexpr float IGNORED_C = -3000.0f;

// fast path params (R3 geometry: best measured total, 72 us)
constexpr int NCHUNK = 8;
constexpr int CHUNK = VOCAB / NCHUNK;   // 16000
constexpr int N4 = CHUNK / 4;           // 4000 float4 per chunk
constexpr int BINS = 8192;              // top 13 bits of monotone key
constexpr int SHIFT = 19;
constexpr int CAP = 512;                // candidate cap == sort width == blockDim

// fallback path params
constexpr int FB_BINS = 8192;
constexpr int FB_SHIFT = 19;
constexpr int FB_CAND = 2048;

// order-preserving f32 -> u32 map (larger float => larger key)
__device__ __forceinline__ unsigned mono(unsigned u) {
    return (u & 0x80000000u) ? ~u : (u | 0x80000000u);
}
__device__ __forceinline__ float inv_mono(unsigned k) {
    unsigned u = (k & 0x80000000u) ? (k ^ 0x80000000u) : ~k;
    return __uint_as_float(u);
}

// ============================================================================
// K1: per (row, chunk): LDS histogram -> wave-0 suffix scan -> collect from
// L2/L3 -> hybrid bitonic sort-512 -> sorted top-256 u64 keys.
// This is round-3's kernel (best measured) minus the register-resident data
// (which silently spilled: ~180 MB of scratch round-trip). Streaming passes
// unrolled x2 to keep two loads in flight.
// ============================================================================
__global__ __launch_bounds__(512)
void k1_topk_chunk(const float* __restrict__ logits,
                   unsigned long long* __restrict__ ws_cand)
{
    __shared__ unsigned hist[BINS];
    __shared__ unsigned part[512];
    __shared__ unsigned long long cand[CAP];
    __shared__ unsigned ccount;
    __shared__ int s_tbin;

    const int tid = threadIdx.x;
    const int row = blockIdx.x >> 3;            // NCHUNK == 8
    const int chunk = blockIdx.x & 7;
    const int gbase = chunk * CHUNK;
    const float4* rp4 = reinterpret_cast<const float4*>(
        logits + (size_t)row * VOCAB + (size_t)gbase);

    for (int i = tid; i < BINS; i += 512) hist[i] = 0u;
    if (tid == 0) ccount = 0u;
    __syncthreads();

    // ---- pass 1: histogram of top-13-bit keys (2 loads in flight) ----
    for (int i = tid; i < N4; i += 1024) {
        const float4 va = rp4[i];
        const bool hb = (i + 512) < N4;
        float4 vb;
        if (hb) vb = rp4[i + 512];
        atomicAdd(&hist[mono(__float_as_uint(va.x)) >> SHIFT], 1u);
        atomicAdd(&hist[mono(__float_as_uint(va.y)) >> SHIFT], 1u);
        atomicAdd(&hist[mono(__float_as_uint(va.z)) >> SHIFT], 1u);
        atomicAdd(&hist[mono(__float_as_uint(va.w)) >> SHIFT], 1u);
        if (hb) {
            atomicAdd(&hist[mono(__float_as_uint(vb.x)) >> SHIFT], 1u);
            atomicAdd(&hist[mono(__float_as_uint(vb.y)) >> SHIFT], 1u);
            atomicAdd(&hist[mono(__float_as_uint(vb.z)) >> SHIFT], 1u);
            atomicAdd(&hist[mono(__float_as_uint(vb.w)) >> SHIFT], 1u);
        }
    }
    __syncthreads();

    // ---- group sums of 16 bins each (rotated reads: ~2-way banks) ----
    {
        unsigned s = 0;
        #pragma unroll
        for (int j = 0; j < 16; ++j)
            s += hist[tid * 16 + ((j + tid) & 15)];
        part[tid] = s;
    }
    __syncthreads();

    // ---- wave 0 only: suffix scan over 512 group sums -> threshold bin ----
    if (tid < 64) {
        const int l = tid;
        const unsigned g0 = part[l * 8 + 0], g1 = part[l * 8 + 1];
        const unsigned g2 = part[l * 8 + 2], g3 = part[l * 8 + 3];
        const unsigned g4 = part[l * 8 + 4], g5 = part[l * 8 + 5];
        const unsigned g6 = part[l * 8 + 6], g7 = part[l * 8 + 7];
        const unsigned s7 = g7;
        const unsigned s6 = s7 + g6;
        const unsigned s5 = s6 + g5;
        const unsigned s4 = s5 + g4;
        const unsigned s3 = s4 + g3;
        const unsigned s2 = s3 + g2;
        const unsigned s1 = s2 + g1;
        const unsigned s0 = s1 + g0;        // lane total
        unsigned suf = s0;                  // inclusive suffix across lanes
        #pragma unroll
        for (int off = 1; off < 64; off <<= 1) {
            unsigned t = __shfl_down(suf, off);
            if (l + off < 64) suf += t;
        }
        const unsigned hi = suf - s0;       // sum over lanes > l
        const bool finder = (hi < (unsigned)K) && (hi + s0 >= (unsigned)K);
        int jj; unsigned base;
        if      (hi + s7 >= (unsigned)K) { jj = 7; base = hi; }
        else if (hi + s6 >= (unsigned)K) { jj = 6; base = hi + s7; }
        else if (hi + s5 >= (unsigned)K) { jj = 5; base = hi + s6; }
        else if (hi + s4 >= (unsigned)K) { jj = 4; base = hi + s5; }
        else if (hi + s3 >= (unsigned)K) { jj = 3; base = hi + s4; }
        else if (hi + s2 >= (unsigned)K) { jj = 2; base = hi + s3; }
        else if (hi + s1 >= (unsigned)K) { jj = 1; base = hi + s2; }
        else                             { jj = 0; base = hi + s1; }
        int tg = l * 8 + jj;
        const unsigned long long fm = __ballot(finder);
        const int src = __ffsll((unsigned long long)fm) - 1;
        tg   = __shfl(tg, src);
        base = __shfl(base, src);
        unsigned h = (l < 16) ? hist[tg * 16 + l] : 0u;
        unsigned suf16 = h;
        #pragma unroll
        for (int off = 1; off < 16; off <<= 1) {
            unsigned t = __shfl_down(suf16, off);
            if (l + off < 16) suf16 += t;
        }
        const bool qual = (l < 16) && (base + suf16 >= (unsigned)K);
        const unsigned long long qm = __ballot(qual);
        if (l == 0) s_tbin = tg * 16 + (63 - __builtin_clzll(qm));
    }
    __syncthreads();

    // ---- pass 2: collect candidates with bin >= tbin (from L2/L3) ----
    const unsigned tb = (unsigned)s_tbin;
#define COLV(vv, off4) { \
    const unsigned k_ = mono(__float_as_uint(vv)); \
    if ((k_ >> SHIFT) >= tb) { \
        const unsigned p_ = atomicAdd(&ccount, 1u); \
        if (p_ < (unsigned)CAP) \
            cand[p_] = ((unsigned long long)k_ << 32) | (unsigned)(~(off4)); \
    } }
    for (int i = tid; i < N4; i += 1024) {
        const float4 va = rp4[i];
        const bool hb = (i + 512) < N4;
        float4 vb;
        if (hb) vb = rp4[i + 512];
        const int ba = gbase + i * 4;
        COLV(va.x, ba + 0) COLV(va.y, ba + 1) COLV(va.z, ba + 2) COLV(va.w, ba + 3)
        if (hb) {
            const int bb = gbase + (i + 512) * 4;
            COLV(vb.x, bb + 0) COLV(vb.y, bb + 1) COLV(vb.z, bb + 2) COLV(vb.w, bb + 3)
        }
    }
#undef COLV
    __syncthreads();
    const unsigned cc = ccount;
    if ((unsigned)tid >= cc) cand[tid] = 0ull;   // pad (always < any candidate)
    __syncthreads();

    // ---- hybrid bitonic sort 512 (u64), descending: shfl j<64, LDS j>=64 ----
    unsigned long long v = cand[tid];
    #pragma unroll
    for (int kk = 2; kk <= CAP; kk <<= 1) {
        for (int j = kk >> 1; j > 0; j >>= 1) {
            const bool keepMax = (((tid & kk) == 0) == ((tid & j) == 0));
            unsigned long long w;
            if (j >= 64) {
                __syncthreads();
                cand[tid] = v;
                __syncthreads();
                w = cand[tid ^ j];
            } else {
                w = __shfl_xor(v, j);
            }
            v = keepMax ? (v >= w ? v : w) : (v <= w ? v : w);
        }
    }

    if (tid < K) ws_cand[(size_t)blockIdx.x * K + tid] = v;
}

// ============================================================================
// K2: per row merge 8 sorted runs (bitonic merge stages only) + pipeline
// (round-3 proven: ~8-10 us)
// ============================================================================
__global__ __launch_bounds__(1024)
void k2_merge(const float* __restrict__ params,
              const unsigned long long* __restrict__ ws_cand,
              float* __restrict__ ws_v, float* __restrict__ ws_csum,
              int* __restrict__ ws_idx, float* __restrict__ ws_p0)
{
    constexpr int N = NCHUNK * K;   // 2048
    __shared__ unsigned long long cand[N];
    __shared__ float red[K];
    __shared__ float sc[K];

    const int row = blockIdx.x;
    const int tid = threadIdx.x;

    // load; reverse odd runs so runs alternate desc/asc (valid bitonic state k=256)
    for (int i = tid; i < N; i += 1024) {
        const int c = i >> 8, pos = i & (K - 1);
        unsigned long long v = ws_cand[(size_t)row * N + i];
        const int dest = (c & 1) ? ((c << 8) | (K - 1 - pos)) : i;
        cand[dest] = v;
    }
    __syncthreads();

    // bitonic merge stages k = 512, 1024, 2048 (descending overall)
    for (int kk2 = 2 * K; kk2 <= N; kk2 <<= 1) {
        for (int j = kk2 >> 1; j > 0; j >>= 1) {
            for (int i = tid; i < N; i += 1024) {
                const int ixj = i ^ j;
                if (ixj > i) {
                    unsigned long long a = cand[i], b = cand[ixj];
                    bool sw = ((i & kk2) == 0) ? (a < b) : (a > b);
                    if (sw) { cand[i] = b; cand[ixj] = a; }
                }
            }
            __syncthreads();
        }
    }

    // pipeline on top-256: topk-mask -> /temp -> softmax -> cumsum
    const bool act = tid < K;
    const float topk_f = params[row * 3 + 0];
    const float temp   = params[row * 3 + 2];
    float v = 0.f;
    int myidx = 0;
    if (act) {
        unsigned long long c = cand[tid];
        float val = inv_mono((unsigned)(c >> 32));
        myidx = (int)(~(unsigned)c);
        float x = (((float)tid) >= topk_f) ? IGNORED_C : val;
        v = x / temp;
        red[tid] = v;
    }
    __syncthreads();
    for (int s = K / 2; s > 0; s >>= 1) {
        if (tid < s) red[tid] = fmaxf(red[tid], red[tid + s]);
        __syncthreads();
    }
    const float m = red[0];
    __syncthreads();
    const float e = act ? expf(v - m) : 0.f;
    if (act) red[tid] = e;
    __syncthreads();
    for (int s = K / 2; s > 0; s >>= 1) {
        if (tid < s) red[tid] += red[tid + s];
        __syncthreads();
    }
    const float ssum = red[0];
    __syncthreads();
    const float p = e / ssum;
    if (act) sc[tid] = p;
    __syncthreads();
    for (int off = 1; off < K; off <<= 1) {
        float t = 0.f;
        if (act && tid >= off) t = sc[tid - off];
        __syncthreads();
        if (act) sc[tid] += t;
        __syncthreads();
    }
    if (act) {
        ws_v[row * K + tid]    = v;
        ws_csum[row * K + tid] = sc[tid];
        ws_idx[row * K + tid]  = myidx;
    }
    if (tid == 0) ws_p0[row] = p;   // probs[0] == csum[0]
}

// ============================================================================
// K3: global-min(p0) -> top-p mask -> softmax -> cumsum -> sample
// ============================================================================
__global__ __launch_bounds__(K)
void k3_sample(const float* __restrict__ params,
               const float* __restrict__ rand_u,
               const float* __restrict__ ws_v,
               const float* __restrict__ ws_csum,
               const int* __restrict__ ws_idx,
               const float* __restrict__ ws_p0,
               int* __restrict__ out)
{
    __shared__ float red[K];
    __shared__ float sc[K];
    const int row = blockIdx.x;
    const int tid = threadIdx.x;

    red[tid] = ws_p0[tid];          // BATCH == 256 == blockDim
    __syncthreads();
    for (int s = K / 2; s > 0; s >>= 1) {
        if (tid < s) red[tid] = fminf(red[tid], red[tid + s]);
        __syncthreads();
    }
    const float tpe = fmaxf(red[0], params[row * 3 + 1]);
    __syncthreads();

    const float csum = ws_csum[row * K + tid];
    const float v0   = ws_v[row * K + tid];
    const float v2 = ((csum > tpe) && (tid != 0)) ? IGNORED_C : v0;
    red[tid] = v2;
    __syncthreads();
    for (int s = K / 2; s > 0; s >>= 1) {
        if (tid < s) red[tid] = fmaxf(red[tid], red[tid + s]);
        __syncthreads();
    }
    const float m = red[0];
    __syncthreads();
    const float e = expf(v2 - m);
    red[tid] = e;
    __syncthreads();
    for (int s = K / 2; s > 0; s >>= 1) {
        if (tid < s) red[tid] += red[tid + s];
        __syncthreads();
    }
    const float ssum = red[0];
    __syncthreads();
    const float p = e / ssum;
    sc[tid] = p;
    __syncthreads();
    for (int off = 1; off < K; off <<= 1) {
        float t = (tid >= off) ? sc[tid - off] : 0.f;
        __syncthreads();
        sc[tid] += t;
        __syncthreads();
    }
    const float ru = rand_u[row];
    red[tid] = (ru > sc[tid]) ? 1.f : 0.f;
    __syncthreads();
    for (int s = K / 2; s > 0; s >>= 1) {
        if (tid < s) red[tid] += red[tid + s];
        __syncthreads();
    }
    if (tid == 0) {
        int sel = (int)red[0];
        if (sel > K - 1) sel = K - 1;
        out[row] = ws_idx[row * K + sel];
    }
}

// ============================================================================
// Fallback (round-1 proven): single block per row, used only if ws too small
// ============================================================================
__global__ __launch_bounds__(1024)
void fb_stage1(const float* __restrict__ logits,
               const float* __restrict__ params,
               float* __restrict__ ws_v,
               float* __restrict__ ws_csum,
               int* __restrict__ ws_idx,
               float* __restrict__ ws_p0)
{
    __shared__ unsigned hist[FB_BINS];
    __shared__ unsigned gsum[128];
    __shared__ unsigned long long cand[FB_CAND];
    __shared__ unsigned ccount;
    __shared__ int tbin;
    __shared__ float sv[K];
    __shared__ float se[K];
    __shared__ int   sidx[K];
    __shared__ float sred;

    const int row = blockIdx.x;
    const int tid = threadIdx.x;
    const float4* rp4 = reinterpret_cast<const float4*>(logits + (size_t)row * VOCAB);

    for (int i = tid; i < FB_BINS; i += 1024) hist[i] = 0u;
    __syncthreads();
    for (int i = tid; i < VOCAB / 4; i += 1024) {
        float4 v = rp4[i];
        atomicAdd(&hist[mono(__float_as_uint(v.x)) >> FB_SHIFT], 1u);
        atomicAdd(&hist[mono(__float_as_uint(v.y)) >> FB_SHIFT], 1u);
        atomicAdd(&hist[mono(__float_as_uint(v.z)) >> FB_SHIFT], 1u);
        atomicAdd(&hist[mono(__float_as_uint(v.w)) >> FB_SHIFT], 1u);
    }
    __syncthreads();
    if (tid < 128) {
        unsigned s = 0;
        for (int i = 0; i < 64; ++i) s += hist[tid * 64 + i];
        gsum[tid] = s;
    }
    __syncthreads();
    if (tid == 0) {
        unsigned acc = 0;
        int g = 127;
        for (; g > 0; --g) {
            if (acc + gsum[g] >= (unsigned)K) break;
            acc += gsum[g];
        }
        int t = g * 64;
        for (int bin = g * 64 + 63; bin >= g * 64; --bin) {
            acc += hist[bin];
            if (acc >= (unsigned)K) { t = bin; break; }
        }
        tbin = t;
        ccount = 0u;
    }
    __syncthreads();
    const unsigned tb = (unsigned)tbin;
    for (int i = tid; i < VOCAB / 4; i += 1024) {
        float4 v = rp4[i];
        const int base = i * 4;
        unsigned kk[4] = { mono(__float_as_uint(v.x)), mono(__float_as_uint(v.y)),
                           mono(__float_as_uint(v.z)), mono(__float_as_uint(v.w)) };
        #pragma unroll
        for (int c = 0; c < 4; ++c) {
            if ((kk[c] >> FB_SHIFT) >= tb) {
                unsigned p = atomicAdd(&ccount, 1u);
                if (p < FB_CAND)
                    cand[p] = ((unsigned long long)kk[c] << 32) | (unsigned)(~(base + c));
            }
        }
    }
    __syncthreads();
    for (int i = tid; i < FB_CAND; i += 1024)
        if ((unsigned)i >= ccount) cand[i] = 0ull;
    __syncthreads();
    for (int k = 2; k <= FB_CAND; k <<= 1) {
        for (int j = k >> 1; j > 0; j >>= 1) {
            for (int i = tid; i < FB_CAND; i += 1024) {
                int ixj = i ^ j;
                if (ixj > i) {
                    unsigned long long a = cand[i], b = cand[ixj];
                    bool sw = ((i & k) == 0) ? (a < b) : (a > b);
                    if (sw) { cand[i] = b; cand[ixj] = a; }
                }
            }
            __syncthreads();
        }
    }
    const float topk_f = params[row * 3 + 0];
    const float temp   = params[row * 3 + 2];
    if (tid < K) {
        unsigned long long c = cand[tid];
        float val = inv_mono((unsigned)(c >> 32));
        sidx[tid] = (int)(~(unsigned)c);
        float v = (((float)tid) >= topk_f) ? IGNORED_C : val;
        sv[tid] = v / temp;
    }
    __syncthreads();
    if (tid == 0) {
        float mm = sv[0];
        for (int i = 1; i < K; ++i) mm = fmaxf(mm, sv[i]);
        sred = mm;
    }
    __syncthreads();
    if (tid < K) se[tid] = expf(sv[tid] - sred);
    __syncthreads();
    if (tid == 0) {
        float s = 0.f;
        for (int i = 0; i < K; ++i) s += se[i];
        sred = s;
    }
    __syncthreads();
    if (tid < K) se[tid] = se[tid] / sred;
    __syncthreads();
    if (tid == 0) {
        float c = 0.f;
        for (int i = 0; i < K; ++i) { c += se[i]; se[i] = c; }
    }
    __syncthreads();
    if (tid < K) {
        ws_v[row * K + tid]    = sv[tid];
        ws_csum[row * K + tid] = se[tid];
        ws_idx[row * K + tid]  = sidx[tid];
    }
    if (tid == 0) ws_p0[row] = se[0];
}

extern "C" void kernel_launch(void* const* d_in, const int* in_sizes, int n_in,
                              void* d_out, int out_size, void* d_ws, size_t ws_size,
                              hipStream_t stream) {
    const float* logits = (const float*)d_in[0];
    const float* params = (const float*)d_in[1];
    const float* randu  = (const float*)d_in[2];
    int* out = (int*)d_out;
    char* ws = (char*)d_ws;

    const size_t cand_bytes = (size_t)BATCH * NCHUNK * K * 8;          // 4 MB
    const size_t tail_bytes = (size_t)3 * BATCH * K * 4 + BATCH * 4;   // 769 KB
    if (ws_size >= cand_bytes + tail_bytes) {
        unsigned long long* ws_cand = (unsigned long long*)ws;
        char* p = ws + cand_bytes;
        float* ws_v    = (float*)(p);
        float* ws_csum = (float*)(p + (size_t)BATCH * K * 4);
        int*   ws_idx  = (int*)  (p + (size_t)2 * BATCH * K * 4);
        float* ws_p0   = (float*)(p + (size_t)3 * BATCH * K * 4);
        hipLaunchKernelGGL(k1_topk_chunk, dim3(BATCH * NCHUNK), dim3(512), 0, stream,
                           logits, ws_cand);
        hipLaunchKernelGGL(k2_merge, dim3(BATCH), dim3(1024), 0, stream,
                           params, ws_cand, ws_v, ws_csum, ws_idx, ws_p0);
        hipLaunchKernelGGL(k3_sample, dim3(BATCH), dim3(K), 0, stream,
                           params, randu, ws_v, ws_csum, ws_idx, ws_p0, out);
    } else {
        float* ws_v    = (float*)(ws);
        float* ws_csum = (float*)(ws + (size_t)BATCH * K * 4);
        int*   ws_idx  = (int*)  (ws + (size_t)2 * BATCH * K * 4);
        float* ws_p0   = (float*)(ws + (size_t)3 * BATCH * K * 4);
        hipLaunchKernelGGL(fb_stage1, dim3(BATCH), dim3(1024), 0, stream,
                           logits, params, ws_v, ws_csum, ws_idx, ws_p0);
        hipLaunchKernelGGL(k3_sample, dim3(BATCH), dim3(K), 0, stream,
                           params, randu, ws_v, ws_csum, ws_idx, ws_p0, out);
    }
}